// Round 1
// baseline (1112.633 us; speedup 1.0000x reference)
//
#include <hip/hip_runtime.h>
#include <math.h>

// Problem sizes (fixed by reference setup_inputs)
constexpr int kB = 8;        // batch
constexpr int kS = 2048;     // seq
constexpr int kH = 1024;     // hidden
constexpr int kN = 262144;   // memory rows
constexpr int kD = 512;      // memory dim
constexpr float kEPS = 1e-8f;

__device__ __forceinline__ float dot4(float4 a, float4 b) {
    return a.x*b.x + a.y*b.y + a.z*b.z + a.w*b.w;
}

__device__ __forceinline__ bool better(float v1, int i1, float v2, int i2) {
    // jax.lax.top_k: higher value wins; ties -> lower index
    return v1 > v2 || (v1 == v2 && i1 < i2);
}

// ---------------------------------------------------------------------------
// 1) xbar[b][h] = mean_s x[b][s][h]   (partial sums via atomicAdd; xbar pre-zeroed)
// grid (16 schunks, 4 hchunks, 8 b), block 256
__global__ void k_xbar(const float* __restrict__ x, float* __restrict__ xbar) {
    int t = threadIdx.x;
    int sc = blockIdx.x, hc = blockIdx.y, b = blockIdx.z;
    int h = hc*256 + t;
    const float* xp = x + ((size_t)b*kS + (size_t)sc*128)*kH + h;
    float acc = 0.f;
    #pragma unroll 8
    for (int s = 0; s < 128; ++s) acc += xp[(size_t)s*kH];
    atomicAdd(&xbar[b*kH + h], acc * (1.0f/2048.0f));
}

// ---------------------------------------------------------------------------
// 2) q[b][:] = normalize(xbar[b] @ Wq)     grid 8, block 256
__global__ void k_q(const float* __restrict__ xbar, const float* __restrict__ Wq,
                    float* __restrict__ q) {
    int t = threadIdx.x, b = blockIdx.x;
    __shared__ float xb[kH];
    __shared__ float red[256];
    for (int i = t; i < kH; i += 256) xb[i] = xbar[b*kH + i];
    __syncthreads();
    float a0 = 0.f, a1 = 0.f;
    for (int h = 0; h < kH; ++h) {
        float xv = xb[h];
        a0 = fmaf(xv, Wq[(size_t)h*kD + t],       a0);
        a1 = fmaf(xv, Wq[(size_t)h*kD + t + 256], a1);
    }
    red[t] = a0*a0 + a1*a1;
    __syncthreads();
    for (int s = 128; s > 0; s >>= 1) {
        if (t < s) red[t] += red[t+s];
        __syncthreads();
    }
    float inv = 1.0f / (sqrtf(red[0]) + kEPS);
    q[b*kD + t]       = a0 * inv;
    q[b*kD + t + 256] = a1 * inv;
}

// ---------------------------------------------------------------------------
// 3) scores[b][n] = (q[b] . memory[n]) / (||memory[n]|| + eps)
// wave-per-row; q fragments in registers. grid 4096, block 256 (4 waves x 16 rows)
__global__ void __launch_bounds__(256) k_scores(const float* __restrict__ mem,
                                                const float* __restrict__ q,
                                                float* __restrict__ scores) {
    int t = threadIdx.x;
    int wave = t >> 6, lane = t & 63;
    int off = lane * 4;
    float4 qa[8], qb[8];
    #pragma unroll
    for (int bb = 0; bb < 8; ++bb) {
        qa[bb] = *(const float4*)(q + bb*kD + off);
        qb[bb] = *(const float4*)(q + bb*kD + 256 + off);
    }
    int row0 = (blockIdx.x*4 + wave) * 16;
    for (int i = 0; i < 16; ++i) {
        int row = row0 + i;
        const float* mp = mem + (size_t)row * kD;
        float4 a = *(const float4*)(mp + off);
        float4 c = *(const float4*)(mp + 256 + off);
        float nr = dot4(a, a) + dot4(c, c);
        float dp[8];
        #pragma unroll
        for (int bb = 0; bb < 8; ++bb)
            dp[bb] = dot4(a, qa[bb]) + dot4(c, qb[bb]);
        #pragma unroll
        for (int m = 32; m > 0; m >>= 1) {
            nr += __shfl_xor(nr, m, 64);
            #pragma unroll
            for (int bb = 0; bb < 8; ++bb) dp[bb] += __shfl_xor(dp[bb], m, 64);
        }
        float inv = 1.0f / (sqrtf(nr) + kEPS);
        float myv = 0.f;
        #pragma unroll
        for (int bb = 0; bb < 8; ++bb) if (lane == bb) myv = dp[bb];
        if (lane < 8) scores[(size_t)lane*kN + row] = myv * inv;
    }
}

// ---------------------------------------------------------------------------
// LDS merge tree: 256 sorted-desc 8-lists -> top-8 at list 0. Caller synced.
__device__ __forceinline__ void merge_tree(float* lv, int* li, int t) {
    for (int m = 128; m > 0; m >>= 1) {
        if (t < m) {
            float ov[8]; int oi[8];
            int ia = 0, ib = 0;
            #pragma unroll
            for (int j = 0; j < 8; ++j) {
                float x1 = lv[t*8 + ia];      int i1 = li[t*8 + ia];
                float x2 = lv[(t+m)*8 + ib];  int i2 = li[(t+m)*8 + ib];
                if (better(x1, i1, x2, i2)) { ov[j] = x1; oi[j] = i1; ++ia; }
                else                        { ov[j] = x2; oi[j] = i2; ++ib; }
            }
            #pragma unroll
            for (int j = 0; j < 8; ++j) { lv[t*8 + j] = ov[j]; li[t*8 + j] = oi[j]; }
        }
        __syncthreads();
    }
}

// 4a) per-chunk top-8: grid (64 chunks, 8 b), block 256; chunk = 4096 scores
__global__ void k_top1(const float* __restrict__ scores,
                       float* __restrict__ candv, int* __restrict__ candi) {
    int t = threadIdx.x, c = blockIdx.x, b = blockIdx.y;
    __shared__ float lv[256*8];
    __shared__ int   li[256*8];
    float v[8]; int ix[8];
    #pragma unroll
    for (int j = 0; j < 8; ++j) { v[j] = -3.0e38f; ix[j] = 0x7fffffff; }
    const float* sp = scores + (size_t)b*kN + (size_t)c*4096;
    #pragma unroll
    for (int i = 0; i < 16; ++i) {
        int n = i*256 + t;
        float s = sp[n];
        int gi = c*4096 + n;
        if (better(s, gi, v[7], ix[7])) {
            v[7] = s; ix[7] = gi;
            #pragma unroll
            for (int j = 7; j > 0; --j) {
                if (better(v[j], ix[j], v[j-1], ix[j-1])) {
                    float tv = v[j]; v[j] = v[j-1]; v[j-1] = tv;
                    int   ti = ix[j]; ix[j] = ix[j-1]; ix[j-1] = ti;
                }
            }
        }
    }
    #pragma unroll
    for (int j = 0; j < 8; ++j) { lv[t*8 + j] = v[j]; li[t*8 + j] = ix[j]; }
    __syncthreads();
    merge_tree(lv, li, t);
    if (t < 8) {
        candv[((size_t)b*64 + c)*8 + t] = lv[t];
        candi[((size_t)b*64 + c)*8 + t] = li[t];
    }
}

// 4b) final top-8 over 512 candidates: grid 8, block 256
__global__ void k_top2(const float* __restrict__ candv, const int* __restrict__ candi,
                       int* __restrict__ topidx) {
    int t = threadIdx.x, b = blockIdx.x;
    __shared__ float lv[256*8];
    __shared__ int   li[256*8];
    float c0 = candv[(size_t)b*512 + 2*t];
    float c1 = candv[(size_t)b*512 + 2*t + 1];
    int   i0 = candi[(size_t)b*512 + 2*t];
    int   i1 = candi[(size_t)b*512 + 2*t + 1];
    float v[8]; int ix[8];
    #pragma unroll
    for (int j = 2; j < 8; ++j) { v[j] = -3.0e38f; ix[j] = 0x7fffffff; }
    if (better(c0, i0, c1, i1)) { v[0]=c0; ix[0]=i0; v[1]=c1; ix[1]=i1; }
    else                        { v[0]=c1; ix[0]=i1; v[1]=c0; ix[1]=i0; }
    #pragma unroll
    for (int j = 0; j < 8; ++j) { lv[t*8 + j] = v[j]; li[t*8 + j] = ix[j]; }
    __syncthreads();
    merge_tree(lv, li, t);
    if (t < 8) topidx[b*8 + t] = li[t];
}

// ---------------------------------------------------------------------------
// 5) retrieved[b][k][:] = memory[idx] / (||memory[idx]|| + eps)
// grid (8 k, 8 b), block 64 (one wave)
__global__ void k_gather(const float* __restrict__ mem, const int* __restrict__ topidx,
                         float* __restrict__ retr) {
    int lane = threadIdx.x;
    int k = blockIdx.x, b = blockIdx.y;
    int row = topidx[b*8 + k];
    const float* mp = mem + (size_t)row * kD;
    float4 a = *(const float4*)(mp + lane*4);
    float4 c = *(const float4*)(mp + 256 + lane*4);
    float nr = dot4(a, a) + dot4(c, c);
    #pragma unroll
    for (int m = 32; m > 0; m >>= 1) nr += __shfl_xor(nr, m, 64);
    float inv = 1.0f / (sqrtf(nr) + kEPS);
    float* rp = retr + ((size_t)(b*8 + k)) * kD;
    float4 oa = make_float4(a.x*inv, a.y*inv, a.z*inv, a.w*inv);
    float4 oc = make_float4(c.x*inv, c.y*inv, c.z*inv, c.w*inv);
    *(float4*)(rp + lane*4) = oa;
    *(float4*)(rp + 256 + lane*4) = oc;
}

// ---------------------------------------------------------------------------
// 6) WqT[d][h] = Wq[h][d]    grid (16 hblk, 8 dblk), block 256, 64x64 tiles
__global__ void k_transpose(const float* __restrict__ Wq, float* __restrict__ WqT) {
    __shared__ float tile[64][65];
    int t = threadIdx.x;
    int h0 = blockIdx.x * 64, d0 = blockIdx.y * 64;
    int r = t >> 6, cidx = t & 63;
    #pragma unroll
    for (int i = 0; i < 16; ++i) {
        int hh = i*4 + r;
        tile[hh][cidx] = Wq[(size_t)(h0 + hh)*kD + d0 + cidx];
    }
    __syncthreads();
    #pragma unroll
    for (int i = 0; i < 16; ++i) {
        int dd = i*4 + r;
        WqT[(size_t)(d0 + dd)*kH + h0 + cidx] = tile[cidx][dd];
    }
}

// ---------------------------------------------------------------------------
// 7) out[b][k][h] = scale * sum_d retr[b][k][d] * W[d][h]   (W is [512][1024])
// grid (8 hchunk, 8 b), block 256
__global__ void k_M(const float* __restrict__ W, const float* __restrict__ retr,
                    float scale, float* __restrict__ out) {
    int t = threadIdx.x;
    int hc = blockIdx.x, b = blockIdx.y;
    __shared__ float rl[8*512];
    for (int i = t; i < 8*512; i += 256) rl[i] = retr[(size_t)b*8*512 + i];
    __syncthreads();
    int h = hc*128 + (t & 127);
    int kg = (t >> 7) * 4;
    float acc0 = 0.f, acc1 = 0.f, acc2 = 0.f, acc3 = 0.f;
    for (int d = 0; d < 512; d += 4) {
        float w0 = W[(size_t)(d+0)*kH + h];
        float w1 = W[(size_t)(d+1)*kH + h];
        float w2 = W[(size_t)(d+2)*kH + h];
        float w3 = W[(size_t)(d+3)*kH + h];
        float4 r0 = *(const float4*)&rl[(kg+0)*512 + d];
        float4 r1 = *(const float4*)&rl[(kg+1)*512 + d];
        float4 r2 = *(const float4*)&rl[(kg+2)*512 + d];
        float4 r3 = *(const float4*)&rl[(kg+3)*512 + d];
        acc0 += w0*r0.x + w1*r0.y + w2*r0.z + w3*r0.w;
        acc1 += w0*r1.x + w1*r1.y + w2*r1.z + w3*r1.w;
        acc2 += w0*r2.x + w1*r2.y + w2*r2.z + w3*r2.w;
        acc3 += w0*r3.x + w1*r3.y + w2*r3.z + w3*r3.w;
    }
    float* op = out + (size_t)b*8*kH + h;
    op[(size_t)(kg+0)*kH] = acc0 * scale;
    op[(size_t)(kg+1)*kH] = acc1 * scale;
    op[(size_t)(kg+2)*kH] = acc2 * scale;
    op[(size_t)(kg+3)*kH] = acc3 * scale;
}

// ---------------------------------------------------------------------------
// 8) fused per-token: logits = x.M1 (scale folded), softmax, out = x + attn.M2
// grid (64 schunk, 8 b), block 256 (4 waves x 8 tokens), 64 KB LDS
__global__ void __launch_bounds__(256) k_fused(const float* __restrict__ x,
                                               const float* __restrict__ m1,
                                               const float* __restrict__ m2,
                                               float* __restrict__ out) {
    int t = threadIdx.x;
    int sc = blockIdx.x, b = blockIdx.y;
    __shared__ float m1l[8192];
    __shared__ float m2l[8192];
    {
        const float4* s1 = (const float4*)(m1 + (size_t)b*8192);
        const float4* s2 = (const float4*)(m2 + (size_t)b*8192);
        float4* d1 = (float4*)m1l;
        float4* d2 = (float4*)m2l;
        for (int i = t; i < 2048; i += 256) { d1[i] = s1[i]; d2[i] = s2[i]; }
    }
    __syncthreads();
    int wave = t >> 6, lane = t & 63;
    int off = lane * 4;
    #pragma unroll 1
    for (int i = 0; i < 8; ++i) {
        int s = sc*32 + wave*8 + i;
        const float* xp = x + ((size_t)b*kS + s)*kH;
        float4 x0 = *(const float4*)(xp + off);
        float4 x1 = *(const float4*)(xp + 256 + off);
        float4 x2 = *(const float4*)(xp + 512 + off);
        float4 x3 = *(const float4*)(xp + 768 + off);
        float p[8];
        #pragma unroll
        for (int k = 0; k < 8; ++k) {
            const float* m1k = m1l + k*1024;
            p[k] = dot4(x0, *(const float4*)(m1k + off))
                 + dot4(x1, *(const float4*)(m1k + 256 + off))
                 + dot4(x2, *(const float4*)(m1k + 512 + off))
                 + dot4(x3, *(const float4*)(m1k + 768 + off));
        }
        #pragma unroll
        for (int m = 32; m > 0; m >>= 1) {
            #pragma unroll
            for (int k = 0; k < 8; ++k) p[k] += __shfl_xor(p[k], m, 64);
        }
        float mx = p[0];
        #pragma unroll
        for (int k = 1; k < 8; ++k) mx = fmaxf(mx, p[k]);
        float e[8];
        float sum = 0.f;
        #pragma unroll
        for (int k = 0; k < 8; ++k) { e[k] = __expf(p[k] - mx); sum += e[k]; }
        float inv = 1.0f / sum;
        float4 o0 = x0, o1 = x1, o2 = x2, o3 = x3;
        #pragma unroll
        for (int k = 0; k < 8; ++k) {
            float a = e[k] * inv;
            const float* m2k = m2l + k*1024;
            float4 w0 = *(const float4*)(m2k + off);
            float4 w1 = *(const float4*)(m2k + 256 + off);
            float4 w2 = *(const float4*)(m2k + 512 + off);
            float4 w3 = *(const float4*)(m2k + 768 + off);
            o0.x = fmaf(a, w0.x, o0.x); o0.y = fmaf(a, w0.y, o0.y);
            o0.z = fmaf(a, w0.z, o0.z); o0.w = fmaf(a, w0.w, o0.w);
            o1.x = fmaf(a, w1.x, o1.x); o1.y = fmaf(a, w1.y, o1.y);
            o1.z = fmaf(a, w1.z, o1.z); o1.w = fmaf(a, w1.w, o1.w);
            o2.x = fmaf(a, w2.x, o2.x); o2.y = fmaf(a, w2.y, o2.y);
            o2.z = fmaf(a, w2.z, o2.z); o2.w = fmaf(a, w2.w, o2.w);
            o3.x = fmaf(a, w3.x, o3.x); o3.y = fmaf(a, w3.y, o3.y);
            o3.z = fmaf(a, w3.z, o3.z); o3.w = fmaf(a, w3.w, o3.w);
        }
        float* op = out + ((size_t)b*kS + s)*kH;
        *(float4*)(op + off)       = o0;
        *(float4*)(op + 256 + off) = o1;
        *(float4*)(op + 512 + off) = o2;
        *(float4*)(op + 768 + off) = o3;
    }
}

// ---------------------------------------------------------------------------
extern "C" void kernel_launch(void* const* d_in, const int* in_sizes, int n_in,
                              void* d_out, int out_size, void* d_ws, size_t ws_size,
                              hipStream_t stream) {
    const float* x   = (const float*)d_in[0];
    const float* mem = (const float*)d_in[1];
    const float* Wq  = (const float*)d_in[2];
    const float* Wo  = (const float*)d_in[3];
    float* out = (float*)d_out;
    float* ws  = (float*)d_ws;

    // workspace layout (floats; all 16B-aligned): total ~11.2 MB
    float* xbar   = ws;                     // 8192
    float* q      = xbar + 8192;            // 4096
    float* scores = q + 4096;               // 2097152
    float* candv  = scores + 2097152;       // 4096
    int*   candi  = (int*)(candv + 4096);   // 4096
    int*   topidx = candi + 4096;           // 64
    float* retr   = (float*)(topidx + 64);  // 32768
    float* wqt    = retr + 32768;           // 524288
    float* m1     = wqt + 524288;           // 65536
    float* m2     = m1 + 65536;             // 65536

    hipMemsetAsync(xbar, 0, 8192 * sizeof(float), stream);
    k_xbar<<<dim3(16, 4, 8), 256, 0, stream>>>(x, xbar);
    k_q<<<8, 256, 0, stream>>>(xbar, Wq, q);
    k_scores<<<4096, 256, 0, stream>>>(mem, q, scores);
    k_top1<<<dim3(64, 8), 256, 0, stream>>>(scores, candv, candi);
    k_top2<<<8, 256, 0, stream>>>(candv, candi, topidx);
    k_gather<<<dim3(8, 8), 64, 0, stream>>>(mem, topidx, retr);
    k_transpose<<<dim3(16, 8), 256, 0, stream>>>(Wq, wqt);
    k_M<<<dim3(8, 8), 256, 0, stream>>>(wqt, retr, 0.04419417382415922f, m1); // 1/sqrt(512)
    k_M<<<dim3(8, 8), 256, 0, stream>>>(Wo,  retr, 1.0f, m2);
    k_fused<<<dim3(64, 8), 256, 0, stream>>>(x, m1, m2, out);
}